// Round 7
// baseline (633.579 us; speedup 1.0000x reference)
//
#include <hip/hip_runtime.h>
#include <hip/hip_bf16.h>
#include <stdint.h>

#define D_IN 4096
#define H_SZ 4096
#define NB   1024
#define NST  128      // K=64 steps across [wih | whh]
#define SLOT64 32768  // ring-slot bytes (one K=64 step of A, fp16 tiled)

typedef float    f32x16 __attribute__((ext_vector_type(16)));
typedef _Float16 half8  __attribute__((ext_vector_type(8)));

// d_ws layout: [wsB 16MiB][partials]
#define WSB_BYTES (256ull * 4 * 1024 * 16)
#define PART_OFF  WSB_BYTES
#define WS_NEED   (PART_OFF + 4096)

// ---- preconvert activations: fp32 -> fp16, tiled [kt][pkt][col1024][8] ----
__global__ __launch_bounds__(256)
void preconv_x(const float* __restrict__ x, const float* __restrict__ hp,
               _Float16* __restrict__ wsB)
{
    const int bx = blockIdx.x;           // 256*4
    const int kt = bx >> 2;
    const int cg = bx & 3;
    const int t  = threadIdx.x;
    const float* X = (kt < 128) ? x : hp;
    const int col = cg * 256 + t;
    const float* src = X + (size_t)(kt & 127) * 32 * NB + col;
    _Float16 h[32];
#pragma unroll
    for (int k = 0; k < 32; ++k) h[k] = (_Float16)src[(size_t)k * NB];
    _Float16* dst = wsB + ((size_t)kt * 4096 + col) * 8;
#pragma unroll
    for (int pkt = 0; pkt < 4; ++pkt)
        *(half8*)(dst + (size_t)pkt * 8192) = *(half8*)(h + pkt * 8);
}

// ---- main: fused W-conversion GEMM on the round-6 counted-wait skeleton.
//      A: fp32 W -> reg (2x dwordx4/thread, preconv_w-style gather, issued
//      2 phases ahead, vmcnt(6)) -> cvt fp16(x64) -> ds_write into the
//      PROVEN 0-conflict tiled layout (4-slot 32KB ring, slot s+1 written
//      during step s). B: per-slice prefetch 2 phases ahead (bb0/bb1,
//      loaded after consuming mfma). Counted lgkm waits 5/6/6/2; one
//      barrier per step. No preconv_w pass. ----
__global__ __launch_bounds__(512, 2)
void lstm_main(const float* __restrict__ wih, const float* __restrict__ whh,
               const _Float16* __restrict__ wsB,
               const float* __restrict__ cp,  const float* __restrict__ bih,
               const float* __restrict__ bhh, float* __restrict__ part)
{
    __shared__ __align__(16) char smem[4 * SLOT64];   // 128 KB
    const int t   = threadIdx.x;
    const int bid = blockIdx.x;

    // XCD map: 4 weight-sharing N-siblings of each mtile per XCD
    const int xcd   = bid & 7;
    const int loc   = bid >> 3;
    const int ntile = loc & 3;
    const int mtile = xcd * 8 + (loc >> 2);
    const int h0    = mtile * 64;
    const int bcol0 = ntile * 256;

    // ---- A staging: thread t handles LDS row r=t&255, region j=2p+(t>>8).
    //      Region j of tile T holds K [T*64+j*8, +8) for all 256 rows;
    //      row r <-> weight row grow = (r&3)*H + h0 + (r>>2) (gate-fastest,
    //      identical to the old preconv_w tiling -> frag/epilogue unchanged).
    const int   rloc = t & 255;
    const int   jhalf = t >> 8;                     // 0..1
    const size_t growS = (size_t)(t & 3) * H_SZ + h0 + (rloc >> 2);
    auto stIssue = [&](float4 (&st)[2], int T, int p) {
        const int Tm = T & 127;
        const float* W = (Tm < 64) ? wih : whh;
        const int j = 2 * p + jhalf;
        const float* src = W + growS * D_IN + (Tm & 63) * 64 + j * 8;
        st[0] = *(const float4*)(src);
        st[1] = *(const float4*)(src + 4);
    };
    auto stWrite = [&](float4 (&st)[2], int slot, int p) {
        const int j = 2 * p + jhalf;
        const float* f = (const float*)st;
        half8 h;
#pragma unroll
        for (int k = 0; k < 8; ++k) h[k] = (_Float16)(f[k] * 64.f);
        *(half8*)(smem + slot * SLOT64 + j * 4096 + rloc * 16) = h;
    };

    // ---- compute mapping: 8 waves as 2(M) x 4(N); wave tile 128 x 64 ----
    const int lane = t & 63;
    const int wv = t >> 6;
    const int wr = wv >> 2;              // 0..1
    const int wc = wv & 3;               // 0..3
    const int frow = lane & 31;
    const int fkg  = lane >> 5;
    const int aRd = (wr * 128 + frow) * 16;

    // B frag loads: per-slice, direct from pre-tiled wsB (512B segments)
    const _Float16* bBase = wsB + ((size_t)fkg * 1024 + bcol0 + wc * 64 + frow) * 8;
    auto ldB1 = [&](half8 (&bb)[2], int step, int ks) {
        const int kt = (2 * step + (ks >> 1)) & 255;
        const _Float16* p = bBase + (size_t)kt * 32768 + (ks & 1) * 16384;
        bb[0] = *(const half8*)(p);
        bb[1] = *(const half8*)(p + 256);
    };

    f32x16 acc[4][2] = {};
    half8 aFa[4], aFb[4];
    auto readA = [&](const char* cur, int ks, half8 (&af)[4]) {
        const int po = (ks >> 1) * 16384 + ((ks & 1) * 2 + fkg) * 4096;
#pragma unroll
        for (int mf = 0; mf < 4; ++mf)
            af[mf] = *(const half8*)(cur + po + aRd + mf * 512);
    };
    auto mfma8 = [&](half8 (&af)[4], half8 (&bb)[2]) {
        __builtin_amdgcn_s_setprio(1);
#pragma unroll
        for (int mf = 0; mf < 4; ++mf)
#pragma unroll
            for (int nf = 0; nf < 2; ++nf)
                acc[mf][nf] = __builtin_amdgcn_mfma_f32_32x32x16_f16(af[mf], bb[nf], acc[mf][nf], 0, 0, 0);
        __builtin_amdgcn_s_setprio(0);
    };

    half8 bb0[2], bb1[2];
    float4 stP[2], stQ[2];

    // ---- prologue: stage tile0 -> slot0; prime in-flight state the loop
    //      expects: stP=(tile1,pair2), stQ=(tile1,pair3), bb0/bb1 = B(0,0/1).
    stIssue(stP, 0, 0); stIssue(stQ, 0, 1);
    asm volatile("s_waitcnt vmcnt(2)" ::: "memory");
    stWrite(stP, 0, 0);
    stIssue(stP, 0, 2);
    asm volatile("s_waitcnt vmcnt(2)" ::: "memory");
    stWrite(stQ, 0, 1);
    stIssue(stQ, 0, 3);
    asm volatile("s_waitcnt vmcnt(2)" ::: "memory");
    stWrite(stP, 0, 2);
    asm volatile("s_waitcnt vmcnt(0)" ::: "memory");
    stWrite(stQ, 0, 3);
    stIssue(stP, 1, 2);                  // consumed (s=0,P0) -> slot1 r45
    stIssue(stQ, 1, 3);                  // consumed (s=0,P1) -> slot1 r67
    ldB1(bb0, 0, 0);
    ldB1(bb1, 0, 1);
    asm volatile("s_waitcnt lgkmcnt(0)" ::: "memory");
    __builtin_amdgcn_s_barrier();

    for (int s = 0; s < NST; ++s) {
        const char* cur = smem + (s & 3) * SLOT64;
        const int slotN = (s + 1) & 3;
        // ---- P0: frag slices 0,1 | write (s-1,2) | issue (s,0) ----
        readA(cur, 0, aFa);
        readA(cur, 1, aFb);
        asm volatile("s_waitcnt vmcnt(6)" ::: "memory");
        stWrite(stP, slotN, 2);
        stIssue(stP, s + 1, 0);
        asm volatile("s_waitcnt lgkmcnt(5)" ::: "memory");
        __builtin_amdgcn_sched_barrier(0);
        mfma8(aFa, bb0);
        ldB1(bb0, s, 2);
        // ---- P1: frag slice 2 | write (s-1,3) | issue (s,1) ----
        readA(cur, 2, aFa);
        asm volatile("s_waitcnt vmcnt(6)" ::: "memory");
        stWrite(stQ, slotN, 3);
        stIssue(stQ, s + 1, 1);
        asm volatile("s_waitcnt lgkmcnt(6)" ::: "memory");
        __builtin_amdgcn_sched_barrier(0);
        mfma8(aFb, bb1);
        ldB1(bb1, s, 3);
        // ---- P2: frag slice 3 | write (s,0) | issue (s,2) ----
        readA(cur, 3, aFb);
        asm volatile("s_waitcnt vmcnt(6)" ::: "memory");
        stWrite(stP, slotN, 0);
        stIssue(stP, s + 2, 2);
        asm volatile("s_waitcnt lgkmcnt(6)" ::: "memory");
        __builtin_amdgcn_sched_barrier(0);
        mfma8(aFa, bb0);
        ldB1(bb0, s + 1, 0);
        // ---- P3: write (s,1) | issue (s,3) | drain writes | barrier ----
        asm volatile("s_waitcnt vmcnt(6)" ::: "memory");
        stWrite(stQ, slotN, 1);
        stIssue(stQ, s + 2, 3);
        asm volatile("s_waitcnt lgkmcnt(2)" ::: "memory");
        __builtin_amdgcn_sched_barrier(0);
        mfma8(aFb, bb1);
        ldB1(bb1, s + 1, 1);
        asm volatile("s_waitcnt lgkmcnt(0)" ::: "memory");
        __builtin_amdgcn_s_barrier();
    }

    // ---- in-register LSTM epilogue ----
    // frag row = gate + 8q + 4*fkg; hid = h0 + wr*32 + mf*8 + 2q + fkg
    float psum = 0.f;
#pragma unroll
    for (int mf = 0; mf < 4; ++mf) {
#pragma unroll
        for (int q = 0; q < 4; ++q) {
            const int hg = h0 + wr * 32 + mf * 8 + 2 * q + fkg;
            const float bi  = bih[0 * H_SZ + hg] + bhh[0 * H_SZ + hg];
            const float bf_ = bih[1 * H_SZ + hg] + bhh[1 * H_SZ + hg];
            const float bg  = bih[2 * H_SZ + hg] + bhh[2 * H_SZ + hg];
            const float bo  = bih[3 * H_SZ + hg] + bhh[3 * H_SZ + hg];
#pragma unroll
            for (int nf = 0; nf < 2; ++nf) {
                const int bcol = bcol0 + wc * 64 + nf * 32 + frow;
                const float ig = acc[mf][nf][q * 4 + 0] * 0.015625f + bi;
                const float fg = acc[mf][nf][q * 4 + 1] * 0.015625f + bf_;
                const float gg = acc[mf][nf][q * 4 + 2] * 0.015625f + bg;
                const float og = acc[mf][nf][q * 4 + 3] * 0.015625f + bo;
                const float i_ = 1.f / (1.f + __expf(-ig));
                const float f_ = 1.f / (1.f + __expf(-fg));
                const float g_ = 1.f - 2.f / (__expf(2.f * gg) + 1.f);
                const float o_ = 1.f / (1.f + __expf(-og));
                const float cpv = cp[(size_t)hg * NB + bcol];
                const float cn = f_ * cpv + i_ * g_;
                const float th = 1.f - 2.f / (__expf(2.f * cn) + 1.f);
                psum += cn + o_ * th;
            }
        }
    }

#pragma unroll
    for (int off2 = 32; off2 > 0; off2 >>= 1)
        psum += __shfl_down(psum, off2);
    float* red = (float*)smem;
    if (lane == 0) red[wv] = psum;
    __syncthreads();
    if (t == 0) {
        float s = 0.f;
#pragma unroll
        for (int i = 0; i < 8; ++i) s += red[i];
        part[bid] = s;
    }
}

// ---- fallback (round-6 kernel, proven) for small ws_size ----
#define FAHI 0
#define FALO 16384
#define FBBR 32768
#define FBUFSZ 49152
#define FNKT 256

__global__ __launch_bounds__(512, 2)
void lstm_fb(const float* __restrict__ x,   const float* __restrict__ hp,
             const float* __restrict__ cp,  const float* __restrict__ wih,
             const float* __restrict__ whh, const float* __restrict__ bih,
             const float* __restrict__ bhh, float* __restrict__ ws)
{
    __shared__ __align__(16) char smem[2 * FBUFSZ];
    const int t   = threadIdx.x;
    const int bid = blockIdx.x;
    const int xcd   = bid & 7;
    const int loc   = bid >> 3;
    const int ntile = loc & 3;
    const int mtile = xcd * 8 + (loc >> 2);
    const int h0    = mtile * 64;
    const int bcol0 = ntile * 256;
    const int sr = t & 255;
    const int sk = t >> 8;
    const size_t aBase = ((size_t)(sr & 3) * H_SZ + h0 + (sr >> 2)) * D_IN + sk * 16;
    const int aw = (sk * 2) * 4096 + sr * 16;
    const size_t bBase = (size_t)(sk * 16) * NB + bcol0 + sr;

    auto loadA = [&](float4 (&av)[4], int hs) {
        const float* W = (hs < 128) ? wih : whh;
        const float* p = W + aBase + (size_t)(hs & 127) * 32;
        av[0] = *(const float4*)(p);
        av[1] = *(const float4*)(p + 4);
        av[2] = *(const float4*)(p + 8);
        av[3] = *(const float4*)(p + 12);
    };
    auto loadB = [&](float (&bv)[16], int hs) {
        const float* X = (hs < 128) ? x : hp;
        const float* p = X + bBase + (size_t)(hs & 127) * 32 * NB;
#pragma unroll
        for (int j = 0; j < 16; ++j) bv[j] = p[(size_t)j * NB];
    };
    auto writeA = [&](float4 (&av)[4], char* base) {
        float f[16];
        *(float4*)(f)      = av[0];
        *(float4*)(f + 4)  = av[1];
        *(float4*)(f + 8)  = av[2];
        *(float4*)(f + 12) = av[3];
#pragma unroll
        for (int q = 0; q < 2; ++q) {
            half8 hi, lo;
#pragma unroll
            for (int j = 0; j < 8; ++j) {
                const float s = f[8 * q + j] * 64.f;
                const _Float16 h = (_Float16)s;
                hi[j] = h;
                lo[j] = (_Float16)(s - (float)h);
            }
            *(half8*)(base + FAHI + aw + q * 4096) = hi;
            *(half8*)(base + FALO + aw + q * 4096) = lo;
        }
    };
    auto writeB = [&](float (&bv)[16], char* base) {
#pragma unroll
        for (int q = 0; q < 2; ++q) {
            half8 vv;
#pragma unroll
            for (int j = 0; j < 8; ++j) vv[j] = (_Float16)bv[8 * q + j];
            *(half8*)(base + FBBR + aw + q * 4096) = vv;
        }
    };

    const int lane = t & 63;
    const int wv = t >> 6;
    const int wr = wv >> 1;
    const int wc = wv & 1;
    const int frow = lane & 31;
    const int fkg  = lane >> 5;
    const int aRd = (wr * 64 + frow) * 16;
    const int bRd = (wc * 128 + frow) * 16;

    f32x16 acc[2][4] = {};
    half8 ah[2], al[2], bq[4];
    auto frag_read = [&](const char* cur, int ksl) {
        const int po = (ksl * 2 + fkg) * 4096;
#pragma unroll
        for (int mf = 0; mf < 2; ++mf) {
            ah[mf] = *(const half8*)(cur + FAHI + po + aRd + mf * 512);
            al[mf] = *(const half8*)(cur + FALO + po + aRd + mf * 512);
        }
#pragma unroll
        for (int nf = 0; nf < 4; ++nf)
            bq[nf] = *(const half8*)(cur + FBBR + po + bRd + nf * 512);
    };
    auto mfma16 = [&]() {
        __builtin_amdgcn_s_setprio(1);
#pragma unroll
        for (int mf = 0; mf < 2; ++mf)
#pragma unroll
            for (int nf = 0; nf < 4; ++nf) {
                acc[mf][nf] = __builtin_amdgcn_mfma_f32_32x32x16_f16(ah[mf], bq[nf], acc[mf][nf], 0, 0, 0);
                acc[mf][nf] = __builtin_amdgcn_mfma_f32_32x32x16_f16(al[mf], bq[nf], acc[mf][nf], 0, 0, 0);
            }
        __builtin_amdgcn_s_setprio(0);
    };
    auto step = [&](int hs, float4 (&avN)[4], float (&bvN)[16],
                    float4 (&avC)[4], float (&bvC)[16]) {
        char* cur = smem + (hs & 1) * FBUFSZ;
        char* nxt = smem + ((hs & 1) ^ 1) * FBUFSZ;
        frag_read(cur, 0);
        if (hs + 2 < FNKT) { loadA(avN, hs + 2); loadB(bvN, hs + 2); }
        mfma16();
        frag_read(cur, 1);
        if (hs + 1 < FNKT) { writeA(avC, nxt); writeB(bvC, nxt); }
        mfma16();
        asm volatile("s_waitcnt lgkmcnt(0)" ::: "memory");
        __builtin_amdgcn_s_barrier();
    };

    float4 avP[4], avQ[4];
    float  bvP[16], bvQ[16];
    loadA(avP, 0); loadB(bvP, 0);
    writeA(avP, smem); writeB(bvP, smem);
    loadA(avQ, 1); loadB(bvQ, 1);
    asm volatile("s_waitcnt lgkmcnt(0)" ::: "memory");
    __builtin_amdgcn_s_barrier();
    for (int h2 = 0; h2 < FNKT; h2 += 2) {
        step(h2,     avP, bvP, avQ, bvQ);
        step(h2 + 1, avQ, bvQ, avP, bvP);
    }

    float psum = 0.f;
#pragma unroll
    for (int mf = 0; mf < 2; ++mf) {
#pragma unroll
        for (int q = 0; q < 4; ++q) {
            const int hg = h0 + wr * 16 + mf * 8 + 2 * q + fkg;
            const float bi  = bih[0 * H_SZ + hg] + bhh[0 * H_SZ + hg];
            const float bf_ = bih[1 * H_SZ + hg] + bhh[1 * H_SZ + hg];
            const float bg  = bih[2 * H_SZ + hg] + bhh[2 * H_SZ + hg];
            const float bo  = bih[3 * H_SZ + hg] + bhh[3 * H_SZ + hg];
#pragma unroll
            for (int nf = 0; nf < 4; ++nf) {
                const int bcol = bcol0 + wc * 128 + nf * 32 + frow;
                const float ig = acc[mf][nf][q * 4 + 0] * 0.015625f + bi;
                const float fg = acc[mf][nf][q * 4 + 1] * 0.015625f + bf_;
                const float gg = acc[mf][nf][q * 4 + 2] * 0.015625f + bg;
                const float og = acc[mf][nf][q * 4 + 3] * 0.015625f + bo;
                const float i_ = 1.f / (1.f + __expf(-ig));
                const float f_ = 1.f / (1.f + __expf(-fg));
                const float g_ = 1.f - 2.f / (__expf(2.f * gg) + 1.f);
                const float o_ = 1.f / (1.f + __expf(-og));
                const float cpv = cp[(size_t)hg * NB + bcol];
                const float cn = f_ * cpv + i_ * g_;
                const float th = 1.f - 2.f / (__expf(2.f * cn) + 1.f);
                psum += cn + o_ * th;
            }
        }
    }
#pragma unroll
    for (int off2 = 32; off2 > 0; off2 >>= 1)
        psum += __shfl_down(psum, off2);
    __syncthreads();
    float* red = (float*)smem;
    if (lane == 0) red[wv] = psum;
    __syncthreads();
    if (t == 0) {
        float s = 0.f;
#pragma unroll
        for (int i = 0; i < 8; ++i) s += red[i];
        ws[bid] = s;
    }
}

__global__ void final_reduce(const float* __restrict__ part, float* __restrict__ out)
{
    const int t = threadIdx.x;   // 256 partials, fp64 accumulation
    double s = (double)part[t];
#pragma unroll
    for (int off = 32; off > 0; off >>= 1)
        s += __shfl_down(s, off);
    __shared__ double r[4];
    if ((t & 63) == 0) r[t >> 6] = s;
    __syncthreads();
    if (t == 0) out[0] = (float)(r[0] + r[1] + r[2] + r[3]);
}

extern "C" void kernel_launch(void* const* d_in, const int* in_sizes, int n_in,
                              void* d_out, int out_size, void* d_ws, size_t ws_size,
                              hipStream_t stream)
{
    const float* x   = (const float*)d_in[0];
    const float* hp  = (const float*)d_in[1];
    const float* cp  = (const float*)d_in[2];
    const float* wih = (const float*)d_in[3];
    const float* whh = (const float*)d_in[4];
    const float* bih = (const float*)d_in[5];
    const float* bhh = (const float*)d_in[6];

    if (ws_size >= (size_t)WS_NEED) {
        _Float16* wsB = (_Float16*)d_ws;
        float* part   = (float*)((char*)d_ws + PART_OFF);
        hipLaunchKernelGGL(preconv_x, dim3(256 * 4), dim3(256), 0, stream, x, hp, wsB);
        hipLaunchKernelGGL(lstm_main, dim3(256), dim3(512), 0, stream,
                           wih, whh, wsB, cp, bih, bhh, part);
        hipLaunchKernelGGL(final_reduce, dim3(1), dim3(256), 0, stream, part, (float*)d_out);
    } else {
        float* part = (float*)d_ws;
        hipLaunchKernelGGL(lstm_fb, dim3(256), dim3(512), 0, stream,
                           x, hp, cp, wih, whh, bih, bhh, part);
        hipLaunchKernelGGL(final_reduce, dim3(1), dim3(256), 0, stream, part, (float*)d_out);
    }
}

// Round 8
// 423.375 us; speedup vs baseline: 1.4965x; 1.4965x over previous
//
#include <hip/hip_runtime.h>
#include <hip/hip_bf16.h>
#include <stdint.h>

#define D_IN 4096
#define H_SZ 4096
#define NB   1024
#define NST  128      // K=64 steps across [wih | whh]
#define SLOT64 32768  // A ring-slot bytes (one K=64 step of A)

typedef float    f32x16 __attribute__((ext_vector_type(16)));
typedef _Float16 half8  __attribute__((ext_vector_type(8)));

// d_ws layout: [wsA 256MiB][wsB 16MiB][partials]
#define WSA_BYTES (64ull * 256 * 1024 * 16)
#define WSB_BYTES (256ull * 4 * 1024 * 16)
#define PART_OFF  (WSA_BYTES + WSB_BYTES)
#define WS_NEED   (PART_OFF + 4096)

__device__ __forceinline__ void gl_lds16(const void* g, void* l) {
    __builtin_amdgcn_global_load_lds(
        (const __attribute__((address_space(1))) unsigned int*)g,
        (__attribute__((address_space(3))) unsigned int*)l, 16, 0, 0);
}

// ---- merged preconvert: blocks [0,2048) = weights fp32->fp16(x64),
//      tiled [mtile64][kt][pkt][row256][8]; blocks [2048,3072) =
//      activations fp32->fp16, tiled [kt][pkt][col1024][8]. ----
__global__ __launch_bounds__(256)
void preconv_all(const float* __restrict__ wih, const float* __restrict__ whh,
                 const float* __restrict__ x,   const float* __restrict__ hp,
                 _Float16* __restrict__ wsA,    _Float16* __restrict__ wsB)
{
    const int bx = blockIdx.x;
    const int t  = threadIdx.x;
    if (bx < 2048) {
        // ---- weights: 64 mtiles * 32 kgroups ----
        const int mtile = bx >> 5;
        const int kg    = bx & 31;
        const int r     = t;             // local row, gate-fastest
        const size_t growg = (size_t)(r & 3) * H_SZ + mtile * 64 + (r >> 2);
        const float* base_ih = wih + growg * D_IN;
        const float* base_hh = whh + growg * D_IN;
#pragma unroll 2
        for (int i = 0; i < 8; ++i) {
            const int kt = kg * 8 + i;
            const float* src = ((kt < 128) ? base_ih : base_hh) + (kt & 127) * 32;
            float4 v[8];
#pragma unroll
            for (int j = 0; j < 8; ++j) v[j] = *(const float4*)(src + 4 * j);
            const float* f = (const float*)v;
            _Float16* dst = wsA + ((size_t)(mtile * 256 + kt) * 1024 + r) * 8;
#pragma unroll
            for (int pkt = 0; pkt < 4; ++pkt) {
                half8 h;
#pragma unroll
                for (int j = 0; j < 8; ++j) h[j] = (_Float16)(f[pkt * 8 + j] * 64.f);
                *(half8*)(dst + (size_t)pkt * 2048) = h;
            }
        }
    } else {
        // ---- activations: 256 kt * 4 colgroups ----
        const int bx2 = bx - 2048;
        const int kt = bx2 >> 2;
        const int cg = bx2 & 3;
        const float* X = (kt < 128) ? x : hp;
        const int col = cg * 256 + t;
        const float* src = X + (size_t)(kt & 127) * 32 * NB + col;
        _Float16 h[32];
#pragma unroll
        for (int k = 0; k < 32; ++k) h[k] = (_Float16)src[(size_t)k * NB];
        _Float16* dst = wsB + ((size_t)kt * 4096 + col) * 8;
#pragma unroll
        for (int pkt = 0; pkt < 4; ++pkt)
            *(half8*)(dst + (size_t)pkt * 8192) = *(half8*)(h + pkt * 8);
    }
}

// ---- main: K=64 steps; A via 4-slot LDS DMA ring (3 ahead), B global->reg.
//      Software-pipelined slices: dual aF buffers, two ds_read batches in
//      flight, counted lgkmcnt(4) per slice (DS retires in order; stream is
//      pure ds_read). ONE barrier + ONE counted vmcnt per step. ----
__global__ __launch_bounds__(512, 2)
void lstm_main(const _Float16* __restrict__ wsA, const _Float16* __restrict__ wsB,
               const float* __restrict__ cp,  const float* __restrict__ bih,
               const float* __restrict__ bhh, float* __restrict__ part)
{
    __shared__ __align__(16) char smem[4 * SLOT64];   // 128 KB
    const int t   = threadIdx.x;
    const int bid = blockIdx.x;

    // XCD map: 4 weight-sharing N-siblings of each mtile per XCD
    const int xcd   = bid & 7;
    const int loc   = bid >> 3;
    const int ntile = loc & 3;
    const int mtile = xcd * 8 + (loc >> 2);
    const int h0    = mtile * 64;
    const int bcol0 = ntile * 256;

    // A staging: 32 KB step tile (two consecutive kt32 tiles), 4 x 8KB quarters
    const _Float16* aBase = wsA + (size_t)mtile * 256 * 8192;
    const int aOffE = t * 8;             // elems
    const int ldsAb = t * 16;            // bytes
    auto issueA = [&](int s, char* slot) {
        const _Float16* a = aBase + (size_t)s * 16384;
        gl_lds16(a + aOffE,         slot + ldsAb);
        gl_lds16(a + aOffE + 4096,  slot + ldsAb + 8192);
        gl_lds16(a + aOffE + 8192,  slot + ldsAb + 16384);
        gl_lds16(a + aOffE + 12288, slot + ldsAb + 24576);
    };

    // compute mapping: 8 waves as 2(M) x 4(N); wave tile 128 rows x 64 cols
    const int lane = t & 63;
    const int wv = t >> 6;
    const int wr = wv >> 2;              // 0..1
    const int wc = wv & 3;               // 0..3
    const int frow = lane & 31;
    const int fkg  = lane >> 5;
    const int aRd = (wr * 128 + frow) * 16;

    // B frag loads, direct from pre-tiled wsB (coalesced 512B segments)
    const _Float16* bBase = wsB + ((size_t)fkg * 1024 + bcol0 + wc * 64 + frow) * 8;
    auto ldB2 = [&](half8 (&bb)[2][2], int s, int half) {
        const int kt = (2 * s + half) & 255;
        const _Float16* p = bBase + (size_t)kt * 32768;
#pragma unroll
        for (int sl = 0; sl < 2; ++sl)
#pragma unroll
            for (int nf = 0; nf < 2; ++nf)
                bb[sl][nf] = *(const half8*)(p + sl * 16384 + nf * 256);
    };

    f32x16 acc[4][2] = {};
    half8 aFa[4], aFb[4];                // double-buffered A fragments
    auto readA = [&](const char* cur, int ks, half8 (&af)[4]) {
        const int po = (ks >> 1) * 16384 + ((ks & 1) * 2 + fkg) * 4096;
#pragma unroll
        for (int mf = 0; mf < 4; ++mf)
            af[mf] = *(const half8*)(cur + po + aRd + mf * 512);
    };
    auto mfma8 = [&](half8 (&af)[4], half8 (&bb)[2]) {
        __builtin_amdgcn_s_setprio(1);
#pragma unroll
        for (int mf = 0; mf < 4; ++mf)
#pragma unroll
            for (int nf = 0; nf < 2; ++nf)
                acc[mf][nf] = __builtin_amdgcn_mfma_f32_32x32x16_f16(af[mf], bb[nf], acc[mf][nf], 0, 0, 0);
        __builtin_amdgcn_s_setprio(0);
    };

    half8 u[2][2], v[2][2];

    // prologue: A 3 steps ahead; B first half of step 0.
    // vmcnt(8): A0 AND A1 guaranteed landed (A2, B(u) in flight).
    issueA(0, smem);
    issueA(1, smem + SLOT64);
    issueA(2, smem + 2 * SLOT64);
    ldB2(u, 0, 0);
    asm volatile("s_waitcnt vmcnt(8)" ::: "memory");
    __builtin_amdgcn_s_barrier();

    for (int s = 0; s < NST; ++s) {
        const char* cur = smem + (s & 3) * SLOT64;
        // P0: issue slices 0,1 | B(v: this step, slices 2-3) | wait slice0
        readA(cur, 0, aFa);
        readA(cur, 1, aFb);
        ldB2(v, s, 1);
        asm volatile("s_waitcnt lgkmcnt(4)" ::: "memory");
        __builtin_amdgcn_sched_barrier(0);
        mfma8(aFa, u[0]);
        // P1: issue slice2 | A(s+3) DMA | wait slice1
        readA(cur, 2, aFa);
        issueA((s + 3) & 127, smem + ((s + 3) & 3) * SLOT64);
        asm volatile("s_waitcnt lgkmcnt(4)" ::: "memory");
        __builtin_amdgcn_sched_barrier(0);
        mfma8(aFb, u[1]);
        // P2: issue slice3 | B(u: next step, slices 0-1) | wait slice2
        readA(cur, 3, aFb);
        ldB2(u, s + 1, 0);
        asm volatile("s_waitcnt lgkmcnt(4)" ::: "memory");
        __builtin_amdgcn_sched_barrier(0);
        mfma8(aFa, v[0]);
        // P3: wait slice3 | mfma | step tail: counted vmcnt + one barrier
        asm volatile("s_waitcnt lgkmcnt(0)" ::: "memory");
        __builtin_amdgcn_sched_barrier(0);
        mfma8(aFb, v[1]);
        // A(s+1) issued in step s-2; newer in FIFO: u(s-1)4 + [v,DMA,u]x2 = 24
        asm volatile("s_waitcnt vmcnt(24)" ::: "memory");
        __builtin_amdgcn_s_barrier();
    }

    // drain stray wrapped DMAs before LDS reuse
    asm volatile("s_waitcnt vmcnt(0)" ::: "memory");
    __builtin_amdgcn_s_barrier();

    // ---- in-register LSTM epilogue ----
    // frag row = (reg&3) + 8q + 4*fkg; gate = reg&3;
    // hid = h0 + wr*32 + mf*8 + 2q + fkg; col = bcol0 + wc*64 + nf*32 + frow
    float psum = 0.f;
#pragma unroll
    for (int mf = 0; mf < 4; ++mf) {
#pragma unroll
        for (int q = 0; q < 4; ++q) {
            const int hg = h0 + wr * 32 + mf * 8 + 2 * q + fkg;
            const float bi  = bih[0 * H_SZ + hg] + bhh[0 * H_SZ + hg];
            const float bf_ = bih[1 * H_SZ + hg] + bhh[1 * H_SZ + hg];
            const float bg  = bih[2 * H_SZ + hg] + bhh[2 * H_SZ + hg];
            const float bo  = bih[3 * H_SZ + hg] + bhh[3 * H_SZ + hg];
#pragma unroll
            for (int nf = 0; nf < 2; ++nf) {
                const int bcol = bcol0 + wc * 64 + nf * 32 + frow;
                const float ig = acc[mf][nf][q * 4 + 0] * 0.015625f + bi;
                const float fg = acc[mf][nf][q * 4 + 1] * 0.015625f + bf_;
                const float gg = acc[mf][nf][q * 4 + 2] * 0.015625f + bg;
                const float og = acc[mf][nf][q * 4 + 3] * 0.015625f + bo;
                const float i_ = 1.f / (1.f + __expf(-ig));
                const float f_ = 1.f / (1.f + __expf(-fg));
                const float g_ = 1.f - 2.f / (__expf(2.f * gg) + 1.f);
                const float o_ = 1.f / (1.f + __expf(-og));
                const float cpv = cp[(size_t)hg * NB + bcol];
                const float cn = f_ * cpv + i_ * g_;
                const float th = 1.f - 2.f / (__expf(2.f * cn) + 1.f);
                psum += cn + o_ * th;
            }
        }
    }

#pragma unroll
    for (int off2 = 32; off2 > 0; off2 >>= 1)
        psum += __shfl_down(psum, off2);
    float* red = (float*)smem;
    if (lane == 0) red[wv] = psum;
    __syncthreads();
    if (t == 0) {
        float s = 0.f;
#pragma unroll
        for (int i = 0; i < 8; ++i) s += red[i];
        part[bid] = s;
    }
}

// ---- fallback (round-6 kernel, proven) for small ws_size ----
#define FAHI 0
#define FALO 16384
#define FBBR 32768
#define FBUFSZ 49152
#define FNKT 256

__global__ __launch_bounds__(512, 2)
void lstm_fb(const float* __restrict__ x,   const float* __restrict__ hp,
             const float* __restrict__ cp,  const float* __restrict__ wih,
             const float* __restrict__ whh, const float* __restrict__ bih,
             const float* __restrict__ bhh, float* __restrict__ ws)
{
    __shared__ __align__(16) char smem[2 * FBUFSZ];
    const int t   = threadIdx.x;
    const int bid = blockIdx.x;
    const int xcd   = bid & 7;
    const int loc   = bid >> 3;
    const int ntile = loc & 3;
    const int mtile = xcd * 8 + (loc >> 2);
    const int h0    = mtile * 64;
    const int bcol0 = ntile * 256;
    const int sr = t & 255;
    const int sk = t >> 8;
    const size_t aBase = ((size_t)(sr & 3) * H_SZ + h0 + (sr >> 2)) * D_IN + sk * 16;
    const int aw = (sk * 2) * 4096 + sr * 16;
    const size_t bBase = (size_t)(sk * 16) * NB + bcol0 + sr;

    auto loadA = [&](float4 (&av)[4], int hs) {
        const float* W = (hs < 128) ? wih : whh;
        const float* p = W + aBase + (size_t)(hs & 127) * 32;
        av[0] = *(const float4*)(p);
        av[1] = *(const float4*)(p + 4);
        av[2] = *(const float4*)(p + 8);
        av[3] = *(const float4*)(p + 12);
    };
    auto loadB = [&](float (&bv)[16], int hs) {
        const float* X = (hs < 128) ? x : hp;
        const float* p = X + bBase + (size_t)(hs & 127) * 32 * NB;
#pragma unroll
        for (int j = 0; j < 16; ++j) bv[j] = p[(size_t)j * NB];
    };
    auto writeA = [&](float4 (&av)[4], char* base) {
        float f[16];
        *(float4*)(f)      = av[0];
        *(float4*)(f + 4)  = av[1];
        *(float4*)(f + 8)  = av[2];
        *(float4*)(f + 12) = av[3];
#pragma unroll
        for (int q = 0; q < 2; ++q) {
            half8 hi, lo;
#pragma unroll
            for (int j = 0; j < 8; ++j) {
                const float s = f[8 * q + j] * 64.f;
                const _Float16 h = (_Float16)s;
                hi[j] = h;
                lo[j] = (_Float16)(s - (float)h);
            }
            *(half8*)(base + FAHI + aw + q * 4096) = hi;
            *(half8*)(base + FALO + aw + q * 4096) = lo;
        }
    };
    auto writeB = [&](float (&bv)[16], char* base) {
#pragma unroll
        for (int q = 0; q < 2; ++q) {
            half8 vv;
#pragma unroll
            for (int j = 0; j < 8; ++j) vv[j] = (_Float16)bv[8 * q + j];
            *(half8*)(base + FBBR + aw + q * 4096) = vv;
        }
    };

    const int lane = t & 63;
    const int wv = t >> 6;
    const int wr = wv >> 1;
    const int wc = wv & 1;
    const int frow = lane & 31;
    const int fkg  = lane >> 5;
    const int aRd = (wr * 64 + frow) * 16;
    const int bRd = (wc * 128 + frow) * 16;

    f32x16 acc[2][4] = {};
    half8 ah[2], al[2], bq[4];
    auto frag_read = [&](const char* cur, int ksl) {
        const int po = (ksl * 2 + fkg) * 4096;
#pragma unroll
        for (int mf = 0; mf < 2; ++mf) {
            ah[mf] = *(const half8*)(cur + FAHI + po + aRd + mf * 512);
            al[mf] = *(const half8*)(cur + FALO + po + aRd + mf * 512);
        }
#pragma unroll
        for (int nf = 0; nf < 4; ++nf)
            bq[nf] = *(const half8*)(cur + FBBR + po + bRd + nf * 512);
    };
    auto mfma16 = [&]() {
        __builtin_amdgcn_s_setprio(1);
#pragma unroll
        for (int mf = 0; mf < 2; ++mf)
#pragma unroll
            for (int nf = 0; nf < 4; ++nf) {
                acc[mf][nf] = __builtin_amdgcn_mfma_f32_32x32x16_f16(ah[mf], bq[nf], acc[mf][nf], 0, 0, 0);
                acc[mf][nf] = __builtin_amdgcn_mfma_f32_32x32x16_f16(al[mf], bq[nf], acc[mf][nf], 0, 0, 0);
            }
        __builtin_amdgcn_s_setprio(0);
    };
    auto step = [&](int hs, float4 (&avN)[4], float (&bvN)[16],
                    float4 (&avC)[4], float (&bvC)[16]) {
        char* cur = smem + (hs & 1) * FBUFSZ;
        char* nxt = smem + ((hs & 1) ^ 1) * FBUFSZ;
        frag_read(cur, 0);
        if (hs + 2 < FNKT) { loadA(avN, hs + 2); loadB(bvN, hs + 2); }
        mfma16();
        frag_read(cur, 1);
        if (hs + 1 < FNKT) { writeA(avC, nxt); writeB(bvC, nxt); }
        mfma16();
        asm volatile("s_waitcnt lgkmcnt(0)" ::: "memory");
        __builtin_amdgcn_s_barrier();
    };

    float4 avP[4], avQ[4];
    float  bvP[16], bvQ[16];
    loadA(avP, 0); loadB(bvP, 0);
    writeA(avP, smem); writeB(bvP, smem);
    loadA(avQ, 1); loadB(bvQ, 1);
    asm volatile("s_waitcnt lgkmcnt(0)" ::: "memory");
    __builtin_amdgcn_s_barrier();
    for (int h2 = 0; h2 < FNKT; h2 += 2) {
        step(h2,     avP, bvP, avQ, bvQ);
        step(h2 + 1, avQ, bvQ, avP, bvP);
    }

    float psum = 0.f;
#pragma unroll
    for (int mf = 0; mf < 2; ++mf) {
#pragma unroll
        for (int q = 0; q < 4; ++q) {
            const int hg = h0 + wr * 16 + mf * 8 + 2 * q + fkg;
            const float bi  = bih[0 * H_SZ + hg] + bhh[0 * H_SZ + hg];
            const float bf_ = bih[1 * H_SZ + hg] + bhh[1 * H_SZ + hg];
            const float bg  = bih[2 * H_SZ + hg] + bhh[2 * H_SZ + hg];
            const float bo  = bih[3 * H_SZ + hg] + bhh[3 * H_SZ + hg];
#pragma unroll
            for (int nf = 0; nf < 4; ++nf) {
                const int bcol = bcol0 + wc * 128 + nf * 32 + frow;
                const float ig = acc[mf][nf][q * 4 + 0] * 0.015625f + bi;
                const float fg = acc[mf][nf][q * 4 + 1] * 0.015625f + bf_;
                const float gg = acc[mf][nf][q * 4 + 2] * 0.015625f + bg;
                const float og = acc[mf][nf][q * 4 + 3] * 0.015625f + bo;
                const float i_ = 1.f / (1.f + __expf(-ig));
                const float f_ = 1.f / (1.f + __expf(-fg));
                const float g_ = 1.f - 2.f / (__expf(2.f * gg) + 1.f);
                const float o_ = 1.f / (1.f + __expf(-og));
                const float cpv = cp[(size_t)hg * NB + bcol];
                const float cn = f_ * cpv + i_ * g_;
                const float th = 1.f - 2.f / (__expf(2.f * cn) + 1.f);
                psum += cn + o_ * th;
            }
        }
    }
#pragma unroll
    for (int off2 = 32; off2 > 0; off2 >>= 1)
        psum += __shfl_down(psum, off2);
    __syncthreads();
    float* red = (float*)smem;
    if (lane == 0) red[wv] = psum;
    __syncthreads();
    if (t == 0) {
        float s = 0.f;
#pragma unroll
        for (int i = 0; i < 8; ++i) s += red[i];
        ws[bid] = s;
    }
}

__global__ void final_reduce(const float* __restrict__ part, float* __restrict__ out)
{
    const int t = threadIdx.x;   // 256 partials, fp64 accumulation
    double s = (double)part[t];
#pragma unroll
    for (int off = 32; off > 0; off >>= 1)
        s += __shfl_down(s, off);
    __shared__ double r[4];
    if ((t & 63) == 0) r[t >> 6] = s;
    __syncthreads();
    if (t == 0) out[0] = (float)(r[0] + r[1] + r[2] + r[3]);
}

extern "C" void kernel_launch(void* const* d_in, const int* in_sizes, int n_in,
                              void* d_out, int out_size, void* d_ws, size_t ws_size,
                              hipStream_t stream)
{
    const float* x   = (const float*)d_in[0];
    const float* hp  = (const float*)d_in[1];
    const float* cp  = (const float*)d_in[2];
    const float* wih = (const float*)d_in[3];
    const float* whh = (const float*)d_in[4];
    const float* bih = (const float*)d_in[5];
    const float* bhh = (const float*)d_in[6];

    if (ws_size >= (size_t)WS_NEED) {
        _Float16* wsA = (_Float16*)d_ws;
        _Float16* wsB = (_Float16*)((char*)d_ws + WSA_BYTES);
        float* part   = (float*)((char*)d_ws + PART_OFF);
        hipLaunchKernelGGL(preconv_all, dim3(2048 + 1024), dim3(256), 0, stream,
                           wih, whh, x, hp, wsA, wsB);
        hipLaunchKernelGGL(lstm_main, dim3(256), dim3(512), 0, stream,
                           wsA, wsB, cp, bih, bhh, part);
        hipLaunchKernelGGL(final_reduce, dim3(1), dim3(256), 0, stream, part, (float*)d_out);
    } else {
        float* part = (float*)d_ws;
        hipLaunchKernelGGL(lstm_fb, dim3(256), dim3(512), 0, stream,
                           x, hp, cp, wih, whh, bih, bhh, part);
        hipLaunchKernelGGL(final_reduce, dim3(1), dim3(256), 0, stream, part, (float*)d_out);
    }
}